// Round 4
// baseline (126.117 us; speedup 1.0000x reference)
//
#include <hip/hip_runtime.h>
#include <math.h>

// Problem constants (B=2, N=4096, T=2048, E=8192, MAX_DELAY=64)
static constexpr int NN = 4096;
static constexpr int TT = 2048;
static constexpr int EE = 8192;
static constexpr int TK = 64;

typedef __attribute__((ext_vector_type(8))) short   short8v;  // 8 bf16 = 4 VGPR
typedef __attribute__((ext_vector_type(4))) float   float4v;  // MFMA acc

__device__ __forceinline__ unsigned cvtpk_bf16(float lo, float hi) {
    unsigned r;                      // D[15:0]=bf16(lo), D[31:16]=bf16(hi), RNE
    asm("v_cvt_pk_bf16_f32 %0, %1, %2" : "=v"(r) : "v"(lo), "v"(hi));
    return r;
}

// ---------------------------------------------------------------------------
// K1: per-node IRF (1024 blocks) + zero cnt (16 blocks)
// ---------------------------------------------------------------------------
__global__ void irf_zero_kernel(const float* __restrict__ params,
                                float* __restrict__ hirf, int* __restrict__ cnt) {
    int blk = blockIdx.x;
    if (blk < 1024) {
        int t = blk * 256 + threadIdx.x;
        int node = t >> 6, lane = t & 63;
        float p = params[node * 2];
        float sp = fmaxf(p, 0.f) + log1pf(expf(-fabsf(p)));   // stable softplus
        float kst = sp + 0.1f;
        float inv = 1.0f / kst;
        float hv = expf(-(float)lane * inv) * inv;
        float s = hv;
        #pragma unroll
        for (int d = 1; d < 64; d <<= 1) s += __shfl_xor(s, d, 64);
        hirf[node * TK + lane] = hv / s;
    } else {
        int i = (blk - 1024) * 256 + threadIdx.x;
        if (i < NN) cnt[i] = 0;
    }
}

// ---------------------------------------------------------------------------
// K2: per-edge composed kernel (4 edges / 256-thr block) + degree count
// ---------------------------------------------------------------------------
__global__ void kedge_count_kernel(const float* __restrict__ hirf,
                                   const int* __restrict__ esrc, const int* __restrict__ etgt,
                                   float* __restrict__ Ke, int* __restrict__ cnt) {
    __shared__ float s_src[4][TK];
    __shared__ float s_tgt[4][TK];
    int lane = threadIdx.x & 63;
    int grp  = threadIdx.x >> 6;
    int e = blockIdx.x * 4 + grp;
    int s = esrc[e], t = etgt[e];
    s_src[grp][lane] = hirf[s * TK + lane];
    s_tgt[grp][lane] = hirf[t * TK + lane];
    __syncthreads();
    float acc = 0.f;
    for (int tau = 0; tau <= lane; ++tau)
        acc += s_tgt[grp][tau] * s_src[grp][lane - tau];
    Ke[e * TK + lane] = acc;
    if (lane == 0) atomicAdd(&cnt[t], 1);
}

// ---------------------------------------------------------------------------
// K3: single-block exclusive scan of cnt + CSR scatter + reset work counter
// ---------------------------------------------------------------------------
__global__ __launch_bounds__(1024)
void scan_scatter_kernel(const int* __restrict__ cnt, int* __restrict__ rowstart,
                         const int* __restrict__ etgt, int* __restrict__ elist,
                         int* __restrict__ wcount) {
    __shared__ int sc[1024];
    __shared__ int scur[NN];
    int t = threadIdx.x;
    if (t == 0) *wcount = 0;                    // reset stealing counter for K4
    int4 v = reinterpret_cast<const int4*>(cnt)[t];
    int s0 = v.x, s1 = s0 + v.y, s2 = s1 + v.z, s3 = s2 + v.w;
    sc[t] = s3;
    __syncthreads();
    for (int off = 1; off < 1024; off <<= 1) {
        int add = (t >= off) ? sc[t - off] : 0;
        __syncthreads();
        sc[t] += add;
        __syncthreads();
    }
    int excl = sc[t] - s3;
    int4 o; o.x = excl; o.y = excl + s0; o.z = excl + s1; o.w = excl + s2;
    reinterpret_cast<int4*>(rowstart)[t] = o;
    reinterpret_cast<int4*>(scur)[t] = o;
    __syncthreads();
    for (int e = t; e < EE; e += 1024) {
        int tg = etgt[e];
        int pos = atomicAdd(&scur[tg], 1);
        elist[pos] = e;
    }
}

// ---------------------------------------------------------------------------
// K4: persistent polyphase MFMA conv with work-stealing.
// 1536 blocks (6/CU), 256 thr = 4 waves = (batch, time-half).
// Flat route stream across stolen targets; double-buffered LDS
// {x bf16, K-Toeplitz tab}; reg prefetch of route i+1 during compute of i.
// 3-slot LDS ring for popped target ids: every ring write/read pair is
// separated by >=1 __syncthreads() (write at advance-to-p, read at
// advance-to-(p+2) two advances later).
// ---------------------------------------------------------------------------
static constexpr int HALO = 80;
static constexpr int XLEN = HALO + TT;          // 2128 bf16 per batch-row
static constexpr int TABS = 96;
static constexpr int TABE = TABS * 16;
static constexpr int CONV_BLOCKS = 1536;

struct __align__(16) ConvBuf {
    unsigned short x[2][XLEN];                  // [batch][time(+halo)]
    unsigned short tab[TABE];                   // Toeplitz table [r][80 + c]
};

__global__ __launch_bounds__(256, 6)
void conv_mfma_kernel(const float* __restrict__ x,
                      const float* __restrict__ hirf, const float* __restrict__ Ke,
                      const int* __restrict__ esrc,
                      const int* __restrict__ elist,
                      const int* __restrict__ rowstart,
                      const int* __restrict__ cnt,
                      int* __restrict__ wcount,
                      float* __restrict__ y) {
    __shared__ ConvBuf sbuf[2];
    __shared__ int s_ring[3];

    const int tid    = threadIdx.x;
    const int l      = tid & 63;
    const int lane16 = l & 15;
    const int h      = l >> 4;
    const int hlo    = h & 1, hhi = h >> 1;
    const int wv     = tid >> 6;
    const int bsel   = wv >> 1;       // batch
    const int half   = wv & 1;        // time half

    // one-time init: x halos + static tab zero entries, both buffers
    for (int idx = tid; idx < 2 * 2 * HALO; idx += 256) {
        int nb = idx / (2 * HALO), rem = idx % (2 * HALO);
        sbuf[nb].x[rem / HALO][rem % HALO] = 0;
    }
    {
        int r2 = tid >> 4, z = tid & 15;
        int c1 = z, c2 = (z <= r2) ? z + 16 : 80 + z;
        sbuf[0].tab[TABS * r2 + c1] = 0; sbuf[0].tab[TABS * r2 + c2] = 0;
        sbuf[1].tab[TABS * r2 + c1] = 0; sbuf[1].tab[TABS * r2 + c2] = 0;
    }
    if (tid == 0) {
        s_ring[0] = atomicAdd(wcount, 1);
        s_ring[1] = atomicAdd(wcount, 1);
        s_ring[2] = atomicAdd(wcount, 1);
    }
    __syncthreads();

    int tgt = s_ring[0];
    if (tgt >= NN) return;
    tgt = __builtin_amdgcn_readfirstlane(tgt);
    int start = __builtin_amdgcn_readfirstlane(rowstart[tgt]);
    int deg   = __builtin_amdgcn_readfirstlane(cnt[tgt]);

    float4v acc[4];
    #pragma unroll
    for (int T = 0; T < 4; ++T) acc[T] = (float4v){0.f, 0.f, 0.f, 0.f};

    float4 px[4]; float pk;
    auto LOADR = [&](int src, const float* Kp) {
        const float4* r0 = reinterpret_cast<const float4*>(x + (size_t)src * TT);
        const float4* r1 = reinterpret_cast<const float4*>(x + ((size_t)NN + src) * TT);
        px[0] = r0[tid]; px[1] = r0[tid + 256];
        px[2] = r1[tid]; px[3] = r1[tid + 256];
        pk = Kp[tid & 63];
    };
    auto WRITE = [&](int nb) {
        #pragma unroll
        for (int c = 0; c < 4; ++c) {
            int bb = c >> 1;
            int u  = (c & 1) ? tid + 256 : tid;
            unsigned lo = cvtpk_bf16(px[c].x, px[c].y);
            unsigned hi = cvtpk_bf16(px[c].z, px[c].w);
            *reinterpret_cast<uint2*>(&sbuf[nb].x[bb][HALO + 4 * u]) = make_uint2(lo, hi);
        }
        unsigned short kb = (unsigned short)(cvtpk_bf16(pk, pk) & 0xffffu);
        int i = tid & 63, rg = tid >> 6;
        #pragma unroll
        for (int rr = 0; rr < 4; ++rr) {
            int r = rg * 4 + rr;
            sbuf[nb].tab[TABS * r + 80 + r - i] = kb;      // value entries c=r-i
        }
    };
    auto COMPUTE = [&](int cb) {
        const unsigned short* tab = sbuf[cb].tab;
        const unsigned short* xb  = sbuf[cb].x[bsel];
        const int abase = TABS * lane16 + 80 + 8 * hlo;
        short8v A0 = *reinterpret_cast<const short8v*>(&tab[abase - 16 * (0 + hhi)]);
        short8v A1 = *reinterpret_cast<const short8v*>(&tab[abase - 16 * (2 + hhi)]);
        short8v A2 = *reinterpret_cast<const short8v*>(&tab[abase - 16 * (4 + hhi)]);
        #pragma unroll
        for (int T = 0; T < 4; ++T) {
            int bb = HALO + 16 * (64 * half + 16 * T + lane16) + 8 * hlo;
            short8v B0 = *reinterpret_cast<const short8v*>(&xb[bb - 16 * (0 + hhi)]);
            acc[T] = __builtin_amdgcn_mfma_f32_16x16x32_bf16(A0, B0, acc[T], 0, 0, 0);
            short8v B1 = *reinterpret_cast<const short8v*>(&xb[bb - 16 * (2 + hhi)]);
            acc[T] = __builtin_amdgcn_mfma_f32_16x16x32_bf16(A1, B1, acc[T], 0, 0, 0);
            short8v B2 = *reinterpret_cast<const short8v*>(&xb[bb - 16 * (4 + hhi)]);
            acc[T] = __builtin_amdgcn_mfma_f32_16x16x32_bf16(A2, B2, acc[T], 0, 0, 0);
        }
    };
    auto STOREY = [&](int t) {
        float* yrow = y + ((size_t)bsel * NN + t) * TT;
        #pragma unroll
        for (int T = 0; T < 4; ++T) {
            int tb = 16 * (64 * half + 16 * T + lane16) + 4 * h;
            float4v v = acc[T];
            __builtin_nontemporal_store(v, reinterpret_cast<float4v*>(yrow + tb));
            acc[T] = (float4v){0.f, 0.f, 0.f, 0.f};
        }
    };

    // prologue: stage route 0 (self) of first target into buf 0
    LOADR(tgt, hirf + (size_t)tgt * TK);
    WRITE(0);
    __syncthreads();

    int cur = 0;
    int rd  = 1;                              // next ring slot to consume
    // consumer (route in buf[cur]) and producer (route last staged) state
    int Ct = tgt, Cd = deg, Cr = 0;
    int Pt = tgt, Ps = start, Pd = deg, Pr = 0;

    while (true) {
        bool valid = true, needPop = false;
        int wr = 0;
        int aPt = Pt, aPs = Ps, aPd = Pd, aPr = Pr + 1;
        if (aPr > aPd) {                      // producer moves to next target
            aPt = s_ring[rd];
            aPt = __builtin_amdgcn_readfirstlane(aPt);
            if (aPt >= NN) {
                valid = false;
            } else {
                aPs = __builtin_amdgcn_readfirstlane(rowstart[aPt]);
                aPd = __builtin_amdgcn_readfirstlane(cnt[aPt]);
                aPr = 0;
                needPop = true;
                wr = (rd + 2) % 3;            // slot last consumed 2 advances ago
                rd = (rd + 1) % 3;
            }
        }
        if (valid) {
            int src; const float* Kp;
            if (aPr == 0) { src = aPt; Kp = hirf + (size_t)aPt * TK; }
            else {
                int e = __builtin_amdgcn_readfirstlane(elist[aPs + aPr - 1]);
                src   = __builtin_amdgcn_readfirstlane(esrc[e]);
                Kp = Ke + (size_t)e * TK;
            }
            LOADR(src, Kp);                   // reg prefetch (global, covered by compute)
            Pt = aPt; Ps = aPs; Pd = aPd; Pr = aPr;
        }
        COMPUTE(cur);
        if (Cr == Cd) STOREY(Ct);             // last route of consumer's target
        if (!valid) break;
        if (needPop && tid == 0) s_ring[wr] = atomicAdd(wcount, 1);
        WRITE(cur ^ 1);
        __syncthreads();                      // publishes WRITE + ring pop
        cur ^= 1;
        Ct = Pt; Cd = Pd; Cr = Pr;            // consumer <- staged route
    }
}

// ---------------------------------------------------------------------------
extern "C" void kernel_launch(void* const* d_in, const int* in_sizes, int n_in,
                              void* d_out, int out_size, void* d_ws, size_t ws_size,
                              hipStream_t stream) {
    const float* x      = (const float*)d_in[0];
    const float* params = (const float*)d_in[1];
    const int*   esrc   = (const int*)d_in[2];
    const int*   etgt   = (const int*)d_in[3];
    float* y = (float*)d_out;

    float* hirf = (float*)d_ws;                        // [NN][64]
    float* Ke   = hirf + (size_t)NN * TK;              // [EE][64]
    int* cnt      = (int*)(Ke + (size_t)EE * TK);      // [NN]
    int* rowstart = cnt + NN;                          // [NN]
    int* elist    = rowstart + NN;                     // [EE]
    int* wcount   = elist + EE;                        // [1]

    hipLaunchKernelGGL(irf_zero_kernel, dim3(1040), dim3(256), 0, stream, params, hirf, cnt);
    hipLaunchKernelGGL(kedge_count_kernel, dim3(EE / 4), dim3(256), 0, stream,
                       hirf, esrc, etgt, Ke, cnt);
    hipLaunchKernelGGL(scan_scatter_kernel, dim3(1), dim3(1024), 0, stream,
                       cnt, rowstart, etgt, elist, wcount);
    hipLaunchKernelGGL(conv_mfma_kernel, dim3(CONV_BLOCKS), dim3(256), 0, stream,
                       x, hirf, Ke, esrc, elist, rowstart, cnt, wcount, y);
}

// Round 5
// 62.811 us; speedup vs baseline: 2.0079x; 2.0079x over previous
//
#include <hip/hip_runtime.h>
#include <math.h>

// Problem constants (B=2, N=4096, T=2048, E=8192, MAX_DELAY=64)
static constexpr int NN = 4096;
static constexpr int TT = 2048;
static constexpr int EE = 8192;
static constexpr int TK = 64;

typedef __attribute__((ext_vector_type(8))) short   short8v;  // 8 bf16 = 4 VGPR
typedef __attribute__((ext_vector_type(4))) float   float4v;  // MFMA acc

__device__ __forceinline__ unsigned cvtpk_bf16(float lo, float hi) {
    unsigned r;                      // D[15:0]=bf16(lo), D[31:16]=bf16(hi), RNE
    asm("v_cvt_pk_bf16_f32 %0, %1, %2" : "=v"(r) : "v"(lo), "v"(hi));
    return r;
}

// ---------------------------------------------------------------------------
// K1: per-node IRF (1024 blocks) + zero cnt (16 blocks)
// ---------------------------------------------------------------------------
__global__ void irf_zero_kernel(const float* __restrict__ params,
                                float* __restrict__ hirf, int* __restrict__ cnt) {
    int blk = blockIdx.x;
    if (blk < 1024) {
        int t = blk * 256 + threadIdx.x;
        int node = t >> 6, lane = t & 63;
        float p = params[node * 2];
        float sp = fmaxf(p, 0.f) + log1pf(expf(-fabsf(p)));   // stable softplus
        float kst = sp + 0.1f;
        float inv = 1.0f / kst;
        float hv = expf(-(float)lane * inv) * inv;
        float s = hv;
        #pragma unroll
        for (int d = 1; d < 64; d <<= 1) s += __shfl_xor(s, d, 64);
        hirf[node * TK + lane] = hv / s;
    } else {
        int i = (blk - 1024) * 256 + threadIdx.x;
        if (i < NN) cnt[i] = 0;
    }
}

// ---------------------------------------------------------------------------
// K2: per-edge composed kernel (4 edges / 256-thr block) + degree count
// ---------------------------------------------------------------------------
__global__ void kedge_count_kernel(const float* __restrict__ hirf,
                                   const int* __restrict__ esrc, const int* __restrict__ etgt,
                                   float* __restrict__ Ke, int* __restrict__ cnt) {
    __shared__ float s_src[4][TK];
    __shared__ float s_tgt[4][TK];
    int lane = threadIdx.x & 63;
    int grp  = threadIdx.x >> 6;
    int e = blockIdx.x * 4 + grp;
    int s = esrc[e], t = etgt[e];
    s_src[grp][lane] = hirf[s * TK + lane];
    s_tgt[grp][lane] = hirf[t * TK + lane];
    __syncthreads();
    float acc = 0.f;
    for (int tau = 0; tau <= lane; ++tau)
        acc += s_tgt[grp][tau] * s_src[grp][lane - tau];
    Ke[e * TK + lane] = acc;
    if (lane == 0) atomicAdd(&cnt[t], 1);
}

// ---------------------------------------------------------------------------
// K3: single-block exclusive scan of cnt + CSR scatter (LDS cursors)
// ---------------------------------------------------------------------------
__global__ __launch_bounds__(1024)
void scan_scatter_kernel(const int* __restrict__ cnt, int* __restrict__ rowstart,
                         const int* __restrict__ etgt, int* __restrict__ elist) {
    __shared__ int sc[1024];
    __shared__ int scur[NN];
    int t = threadIdx.x;
    int4 v = reinterpret_cast<const int4*>(cnt)[t];
    int s0 = v.x, s1 = s0 + v.y, s2 = s1 + v.z, s3 = s2 + v.w;
    sc[t] = s3;
    __syncthreads();
    for (int off = 1; off < 1024; off <<= 1) {
        int add = (t >= off) ? sc[t - off] : 0;
        __syncthreads();
        sc[t] += add;
        __syncthreads();
    }
    int excl = sc[t] - s3;
    int4 o; o.x = excl; o.y = excl + s0; o.z = excl + s1; o.w = excl + s2;
    reinterpret_cast<int4*>(rowstart)[t] = o;
    reinterpret_cast<int4*>(scur)[t] = o;
    __syncthreads();
    for (int e = t; e < EE; e += 1024) {
        int tg = etgt[e];
        int pos = atomicAdd(&scur[tg], 1);
        elist[pos] = e;
    }
}

// ---------------------------------------------------------------------------
// K4: polyphase MFMA conv.  One block per (target, batch); 128 thr = 2 waves
// (wave = time-half).  Routes (self + incoming edges) iterate with
// double-buffered LDS {x bf16, K-Toeplitz tab} and reg prefetch of route i+1
// during compute of route i; route-metadata prefetched one further ahead.
//
//   y[16a+r] = sum_{delta,p} C[r][16*delta+p] * x[16*(a-delta)+p]
//   C[r][16*delta+p] = K_clip[r - p + 16*delta]     (zero outside [0,64))
//
// bid = 2*tgt + b: the two batch-blocks of a target run adjacent ->
// they fetch the SAME x rows concurrently (one HBM fetch serves both).
// LDS/block = 14.3 KB -> 10 blocks/CU resident (vs 6 in the fused-batch
// version) for latency hiding.
// ---------------------------------------------------------------------------
static constexpr int HALO = 80;                 // covers delta<=5 lookback
static constexpr int XLEN = HALO + TT;          // 2128 bf16
static constexpr int TABS = 96;
static constexpr int TABE = TABS * 16;          // 1536

struct __align__(16) ConvBuf {
    unsigned short x[XLEN];                     // 4256 B
    unsigned short tab[TABE];                   // 3072 B
};                                              // 7328 B; x2 bufs = 14656 B

__global__ __launch_bounds__(128)
void conv_mfma_kernel(const float* __restrict__ x,
                      const float* __restrict__ hirf, const float* __restrict__ Ke,
                      const int* __restrict__ esrc,
                      const int* __restrict__ elist,
                      const int* __restrict__ rowstart,
                      const int* __restrict__ cnt,
                      float* __restrict__ y) {
    __shared__ ConvBuf sbuf[2];

    const int tid    = threadIdx.x;
    const int bid    = blockIdx.x;
    const int b      = bid & 1;                 // batch
    const int tgt    = bid >> 1;
    const int l      = tid & 63;
    const int lane16 = l & 15;
    const int h      = l >> 4;
    const int hlo    = h & 1, hhi = h >> 1;
    const int half   = tid >> 6;                // time half (wave id)

    // one-time init: x halos + static tab zero entries, both buffers
    for (int idx = tid; idx < 2 * HALO; idx += 128) {
        int nb = idx / HALO;
        sbuf[nb].x[idx % HALO] = 0;
    }
    {
        int z = tid & 15;
        #pragma unroll
        for (int rr = 0; rr < 2; ++rr) {
            int r2 = (tid >> 4) + 8 * rr;       // rows 0..15
            int c1 = z, c2 = (z <= r2) ? z + 16 : 80 + z;
            sbuf[0].tab[TABS * r2 + c1] = 0; sbuf[0].tab[TABS * r2 + c2] = 0;
            sbuf[1].tab[TABS * r2 + c1] = 0; sbuf[1].tab[TABS * r2 + c2] = 0;
        }
    }

    float4v acc[4];
    #pragma unroll
    for (int T = 0; T < 4; ++T) acc[T] = (float4v){0.f, 0.f, 0.f, 0.f};

    float4 px[4]; float pk;
    auto LOADR = [&](int src, const float* Kp) {
        const float4* r0 = reinterpret_cast<const float4*>(x + ((size_t)b * NN + src) * TT);
        #pragma unroll
        for (int c = 0; c < 4; ++c) px[c] = r0[tid + 128 * c];
        pk = Kp[l];
    };
    auto WRITE = [&](int nb) {
        #pragma unroll
        for (int c = 0; c < 4; ++c) {
            int u = tid + 128 * c;
            unsigned lo = cvtpk_bf16(px[c].x, px[c].y);
            unsigned hi = cvtpk_bf16(px[c].z, px[c].w);
            *reinterpret_cast<uint2*>(&sbuf[nb].x[HALO + 4 * u]) = make_uint2(lo, hi);
        }
        unsigned short kb = (unsigned short)(cvtpk_bf16(pk, pk) & 0xffffu);
        int rg = tid >> 6;                      // 0..1
        #pragma unroll
        for (int rr = 0; rr < 8; ++rr) {
            int r = rg * 8 + rr;                // 0..15
            sbuf[nb].tab[TABS * r + 80 + r - l] = kb;      // value entries c=r-i
        }
    };
    auto COMPUTE = [&](int cb) {
        const unsigned short* tab = sbuf[cb].tab;
        const unsigned short* xb  = sbuf[cb].x;
        const int abase = TABS * lane16 + 80 + 8 * hlo;
        short8v A0 = *reinterpret_cast<const short8v*>(&tab[abase - 16 * (0 + hhi)]);
        short8v A1 = *reinterpret_cast<const short8v*>(&tab[abase - 16 * (2 + hhi)]);
        short8v A2 = *reinterpret_cast<const short8v*>(&tab[abase - 16 * (4 + hhi)]);
        #pragma unroll
        for (int T = 0; T < 4; ++T) {
            int bb = HALO + 16 * (64 * half + 16 * T + lane16) + 8 * hlo;
            short8v B0 = *reinterpret_cast<const short8v*>(&xb[bb - 16 * (0 + hhi)]);
            acc[T] = __builtin_amdgcn_mfma_f32_16x16x32_bf16(A0, B0, acc[T], 0, 0, 0);
            short8v B1 = *reinterpret_cast<const short8v*>(&xb[bb - 16 * (2 + hhi)]);
            acc[T] = __builtin_amdgcn_mfma_f32_16x16x32_bf16(A1, B1, acc[T], 0, 0, 0);
            short8v B2 = *reinterpret_cast<const short8v*>(&xb[bb - 16 * (4 + hhi)]);
            acc[T] = __builtin_amdgcn_mfma_f32_16x16x32_bf16(A2, B2, acc[T], 0, 0, 0);
        }
    };

    // block-uniform target metadata
    int start = __builtin_amdgcn_readfirstlane(rowstart[tgt]);
    int deg   = __builtin_amdgcn_readfirstlane(cnt[tgt]);
    int nroutes = deg + 1;

    // prologue: stage route 0 (self); overlap metadata fetch with px latency
    LOADR(tgt, hirf + (size_t)tgt * TK);
    int eN = 0, srcN = 0;
    if (deg > 0) {
        eN   = __builtin_amdgcn_readfirstlane(elist[start]);
        srcN = __builtin_amdgcn_readfirstlane(esrc[eN]);
    }
    WRITE(0);
    __syncthreads();

    int cur = 0;
    for (int i = 0; i < nroutes; ++i) {
        if (i + 1 < nroutes) {
            LOADR(srcN, Ke + (size_t)eN * TK);            // prefetch route i+1
            if (i + 2 < nroutes) {                        // metadata for i+2
                eN   = __builtin_amdgcn_readfirstlane(elist[start + i + 1]);
                srcN = __builtin_amdgcn_readfirstlane(esrc[eN]);
            }
        }
        COMPUTE(cur);
        if (i + 1 < nroutes) {
            WRITE(cur ^ 1);
            __syncthreads();
            cur ^= 1;
        }
    }

    float* yrow = y + ((size_t)b * NN + tgt) * TT;
    #pragma unroll
    for (int T = 0; T < 4; ++T) {
        int tb = 16 * (64 * half + 16 * T + lane16) + 4 * h;
        float4v v = acc[T];
        __builtin_nontemporal_store(v, reinterpret_cast<float4v*>(yrow + tb));
    }
}

// ---------------------------------------------------------------------------
extern "C" void kernel_launch(void* const* d_in, const int* in_sizes, int n_in,
                              void* d_out, int out_size, void* d_ws, size_t ws_size,
                              hipStream_t stream) {
    const float* x      = (const float*)d_in[0];
    const float* params = (const float*)d_in[1];
    const int*   esrc   = (const int*)d_in[2];
    const int*   etgt   = (const int*)d_in[3];
    float* y = (float*)d_out;

    float* hirf = (float*)d_ws;                        // [NN][64]
    float* Ke   = hirf + (size_t)NN * TK;              // [EE][64]
    int* cnt      = (int*)(Ke + (size_t)EE * TK);      // [NN]
    int* rowstart = cnt + NN;                          // [NN]
    int* elist    = rowstart + NN;                     // [EE]

    hipLaunchKernelGGL(irf_zero_kernel, dim3(1040), dim3(256), 0, stream, params, hirf, cnt);
    hipLaunchKernelGGL(kedge_count_kernel, dim3(EE / 4), dim3(256), 0, stream,
                       hirf, esrc, etgt, Ke, cnt);
    hipLaunchKernelGGL(scan_scatter_kernel, dim3(1), dim3(1024), 0, stream,
                       cnt, rowstart, etgt, elist);
    hipLaunchKernelGGL(conv_mfma_kernel, dim3(NN * 2), dim3(128), 0, stream,
                       x, hirf, Ke, esrc, elist, rowstart, cnt, y);
}

// Round 6
// 53.850 us; speedup vs baseline: 2.3420x; 1.1664x over previous
//
#include <hip/hip_runtime.h>
#include <math.h>

// Problem constants (B=2, N=4096, T=2048, E=8192, MAX_DELAY=64)
static constexpr int NN = 4096;
static constexpr int TT = 2048;
static constexpr int EE = 8192;
static constexpr int TK = 64;
static constexpr int CAP = 32;                  // max in-degree (Poisson lam=2; 15-sigma margin)

typedef __attribute__((ext_vector_type(8))) short   short8v;  // 8 bf16 = 4 VGPR
typedef __attribute__((ext_vector_type(4))) float   float4v;  // MFMA acc

__device__ __forceinline__ unsigned cvtpk_bf16(float lo, float hi) {
    unsigned r;                      // D[15:0]=bf16(lo), D[31:16]=bf16(hi), RNE
    asm("v_cvt_pk_bf16_f32 %0, %1, %2" : "=v"(r) : "v"(lo), "v"(hi));
    return r;
}

// ---------------------------------------------------------------------------
// K1: per-node IRF (1024 blocks) + zero cnt (16 blocks)
// ---------------------------------------------------------------------------
__global__ void irf_zero_kernel(const float* __restrict__ params,
                                float* __restrict__ hirf, int* __restrict__ cnt) {
    int blk = blockIdx.x;
    if (blk < 1024) {
        int t = blk * 256 + threadIdx.x;
        int node = t >> 6, lane = t & 63;
        float p = params[node * 2];
        float sp = fmaxf(p, 0.f) + log1pf(expf(-fabsf(p)));   // stable softplus
        float kst = sp + 0.1f;
        float inv = 1.0f / kst;
        float hv = expf(-(float)lane * inv) * inv;
        float s = hv;
        #pragma unroll
        for (int d = 1; d < 64; d <<= 1) s += __shfl_xor(s, d, 64);
        hirf[node * TK + lane] = hv / s;
    } else {
        int i = (blk - 1024) * 256 + threadIdx.x;
        if (i < NN) cnt[i] = 0;
    }
}

// ---------------------------------------------------------------------------
// K2: per-edge composed kernel (4 edges / 256-thr block) + capped-list scatter
// ---------------------------------------------------------------------------
__global__ void kedge_scatter_kernel(const float* __restrict__ hirf,
                                     const int* __restrict__ esrc, const int* __restrict__ etgt,
                                     float* __restrict__ Ke, int* __restrict__ cnt,
                                     int2* __restrict__ elist2) {
    __shared__ float s_src[4][TK];
    __shared__ float s_tgt[4][TK];
    int lane = threadIdx.x & 63;
    int grp  = threadIdx.x >> 6;
    int e = blockIdx.x * 4 + grp;
    int s = esrc[e], t = etgt[e];
    s_src[grp][lane] = hirf[s * TK + lane];
    s_tgt[grp][lane] = hirf[t * TK + lane];
    __syncthreads();
    float acc = 0.f;
    for (int tau = 0; tau <= lane; ++tau)
        acc += s_tgt[grp][tau] * s_src[grp][lane - tau];
    Ke[e * TK + lane] = acc;
    if (lane == 0) {
        int pos = atomicAdd(&cnt[t], 1);
        if (pos < CAP) elist2[t * CAP + pos] = make_int2(e, s);
    }
}

// ---------------------------------------------------------------------------
// K4: polyphase MFMA conv.  One block per (target, batch); 128 thr = 2 waves
// (wave = time-half).  Routes (self + incoming edges) iterate with
// double-buffered LDS {x bf16, K-Toeplitz tab} and a 2-DEEP register
// prefetch: route i+2's global loads issue ~2 COMPUTEs before consumption
// (pxA/pxB named sets, unroll-2 loop -> all indexing static).
//
//   y[16a+r] = sum_{delta,p} C[r][16*delta+p] * x[16*(a-delta)+p]
//   C[r][16*delta+p] = K_clip[r - p + 16*delta]     (zero outside [0,64))
// ---------------------------------------------------------------------------
static constexpr int HALO = 80;                 // covers delta<=5 lookback
static constexpr int XLEN = HALO + TT;          // 2128 bf16
static constexpr int TABS = 96;
static constexpr int TABE = TABS * 16;          // 1536

struct __align__(16) ConvBuf {
    unsigned short x[XLEN];                     // 4256 B
    unsigned short tab[TABE];                   // 3072 B
};                                              // 7328 B; x2 bufs = 14656 B

__global__ __launch_bounds__(128)
void conv_mfma_kernel(const float* __restrict__ x,
                      const float* __restrict__ hirf, const float* __restrict__ Ke,
                      const int2* __restrict__ elist2,
                      const int* __restrict__ cnt,
                      float* __restrict__ y) {
    __shared__ ConvBuf sbuf[2];

    const int tid    = threadIdx.x;
    const int bid    = blockIdx.x;
    const int b      = bid & 1;                 // batch
    const int tgt    = bid >> 1;
    const int l      = tid & 63;
    const int lane16 = l & 15;
    const int h      = l >> 4;
    const int hlo    = h & 1, hhi = h >> 1;
    const int half   = tid >> 6;                // time half (wave id)

    // one-time init: x halos + static tab zero entries, both buffers
    for (int idx = tid; idx < 2 * HALO; idx += 128) {
        int nb = idx / HALO;
        sbuf[nb].x[idx % HALO] = 0;
    }
    {
        int z = tid & 15;
        #pragma unroll
        for (int rr = 0; rr < 2; ++rr) {
            int r2 = (tid >> 4) + 8 * rr;       // rows 0..15
            int c1 = z, c2 = (z <= r2) ? z + 16 : 80 + z;
            sbuf[0].tab[TABS * r2 + c1] = 0; sbuf[0].tab[TABS * r2 + c2] = 0;
            sbuf[1].tab[TABS * r2 + c1] = 0; sbuf[1].tab[TABS * r2 + c2] = 0;
        }
    }

    float4v acc[4];
    #pragma unroll
    for (int T = 0; T < 4; ++T) acc[T] = (float4v){0.f, 0.f, 0.f, 0.f};

    const float4* xbase = reinterpret_cast<const float4*>(x + (size_t)b * NN * TT);

    float4 pxA[4], pxB[4]; float pkA, pkB;

    auto LOAD_A = [&](int src, const float* Kp) {
        const float4* r0 = xbase + (size_t)src * (TT / 4);
        #pragma unroll
        for (int c = 0; c < 4; ++c) pxA[c] = r0[tid + 128 * c];
        pkA = Kp[l];
    };
    auto LOAD_B = [&](int src, const float* Kp) {
        const float4* r0 = xbase + (size_t)src * (TT / 4);
        #pragma unroll
        for (int c = 0; c < 4; ++c) pxB[c] = r0[tid + 128 * c];
        pkB = Kp[l];
    };
    auto WRITE_A = [&](int nb) {
        #pragma unroll
        for (int c = 0; c < 4; ++c) {
            int u = tid + 128 * c;
            unsigned lo = cvtpk_bf16(pxA[c].x, pxA[c].y);
            unsigned hi = cvtpk_bf16(pxA[c].z, pxA[c].w);
            *reinterpret_cast<uint2*>(&sbuf[nb].x[HALO + 4 * u]) = make_uint2(lo, hi);
        }
        unsigned short kb = (unsigned short)(cvtpk_bf16(pkA, pkA) & 0xffffu);
        int rg = tid >> 6;
        #pragma unroll
        for (int rr = 0; rr < 8; ++rr) {
            int r = rg * 8 + rr;
            sbuf[nb].tab[TABS * r + 80 + r - l] = kb;
        }
    };
    auto WRITE_B = [&](int nb) {
        #pragma unroll
        for (int c = 0; c < 4; ++c) {
            int u = tid + 128 * c;
            unsigned lo = cvtpk_bf16(pxB[c].x, pxB[c].y);
            unsigned hi = cvtpk_bf16(pxB[c].z, pxB[c].w);
            *reinterpret_cast<uint2*>(&sbuf[nb].x[HALO + 4 * u]) = make_uint2(lo, hi);
        }
        unsigned short kb = (unsigned short)(cvtpk_bf16(pkB, pkB) & 0xffffu);
        int rg = tid >> 6;
        #pragma unroll
        for (int rr = 0; rr < 8; ++rr) {
            int r = rg * 8 + rr;
            sbuf[nb].tab[TABS * r + 80 + r - l] = kb;
        }
    };
    auto COMPUTE = [&](int cb) {
        const unsigned short* tab = sbuf[cb].tab;
        const unsigned short* xb  = sbuf[cb].x;
        const int abase = TABS * lane16 + 80 + 8 * hlo;
        short8v A0 = *reinterpret_cast<const short8v*>(&tab[abase - 16 * (0 + hhi)]);
        short8v A1 = *reinterpret_cast<const short8v*>(&tab[abase - 16 * (2 + hhi)]);
        short8v A2 = *reinterpret_cast<const short8v*>(&tab[abase - 16 * (4 + hhi)]);
        #pragma unroll
        for (int T = 0; T < 4; ++T) {
            int bb = HALO + 16 * (64 * half + 16 * T + lane16) + 8 * hlo;
            short8v B0 = *reinterpret_cast<const short8v*>(&xb[bb - 16 * (0 + hhi)]);
            acc[T] = __builtin_amdgcn_mfma_f32_16x16x32_bf16(A0, B0, acc[T], 0, 0, 0);
            short8v B1 = *reinterpret_cast<const short8v*>(&xb[bb - 16 * (2 + hhi)]);
            acc[T] = __builtin_amdgcn_mfma_f32_16x16x32_bf16(A1, B1, acc[T], 0, 0, 0);
            short8v B2 = *reinterpret_cast<const short8v*>(&xb[bb - 16 * (4 + hhi)]);
            acc[T] = __builtin_amdgcn_mfma_f32_16x16x32_bf16(A2, B2, acc[T], 0, 0, 0);
        }
    };

    // ---- metadata + prologue ----
    int deg = __builtin_amdgcn_readfirstlane(cnt[tgt]);
    if (deg > CAP) deg = CAP;
    const int nr = deg + 1;                     // routes: self + edges
    int mdE = 0, mdS = 0;                       // metadata for next route to stage

    LOAD_A(tgt, hirf + (size_t)tgt * TK);       // route 0 = self -> set A
    if (nr > 1) {
        int2 m = elist2[tgt * CAP];
        mdE = __builtin_amdgcn_readfirstlane(m.x);
        mdS = __builtin_amdgcn_readfirstlane(m.y);
        LOAD_B(mdS, Ke + (size_t)mdE * TK);     // route 1 -> set B
        if (nr > 2) {
            int2 m2 = elist2[tgt * CAP + 1];
            mdE = __builtin_amdgcn_readfirstlane(m2.x);
            mdS = __builtin_amdgcn_readfirstlane(m2.y);
        }
    }
    WRITE_A(0);                                 // pxA issued well before this wait
    __syncthreads();

    // ---- main loop: route r lives in buf[r&1], px set[r&1]; unroll 2 ----
    int i = 0;
    while (true) {
        // even i: compute route i (buf0); stage route i+2 into set A
        if (i + 2 < nr) {
            LOAD_A(mdS, Ke + (size_t)mdE * TK);
            if (i + 3 < nr) {
                int2 m = elist2[tgt * CAP + i + 2];
                mdE = __builtin_amdgcn_readfirstlane(m.x);
                mdS = __builtin_amdgcn_readfirstlane(m.y);
            }
        }
        COMPUTE(0);
        if (i + 1 >= nr) break;
        WRITE_B(1);                             // route i+1 (loads issued at i-1)
        __syncthreads();
        ++i;
        // odd i: compute route i (buf1); stage route i+2 into set B
        if (i + 2 < nr) {
            LOAD_B(mdS, Ke + (size_t)mdE * TK);
            if (i + 3 < nr) {
                int2 m = elist2[tgt * CAP + i + 2];
                mdE = __builtin_amdgcn_readfirstlane(m.x);
                mdS = __builtin_amdgcn_readfirstlane(m.y);
            }
        }
        COMPUTE(1);
        if (i + 1 >= nr) break;
        WRITE_A(0);
        __syncthreads();
        ++i;
    }

    float* yrow = y + ((size_t)b * NN + tgt) * TT;
    #pragma unroll
    for (int T = 0; T < 4; ++T) {
        int tb = 16 * (64 * half + 16 * T + lane16) + 4 * h;
        float4v v = acc[T];
        __builtin_nontemporal_store(v, reinterpret_cast<float4v*>(yrow + tb));
    }
}

// ---------------------------------------------------------------------------
extern "C" void kernel_launch(void* const* d_in, const int* in_sizes, int n_in,
                              void* d_out, int out_size, void* d_ws, size_t ws_size,
                              hipStream_t stream) {
    const float* x      = (const float*)d_in[0];
    const float* params = (const float*)d_in[1];
    const int*   esrc   = (const int*)d_in[2];
    const int*   etgt   = (const int*)d_in[3];
    float* y = (float*)d_out;

    float* hirf = (float*)d_ws;                        // [NN][64]   1 MB
    float* Ke   = hirf + (size_t)NN * TK;              // [EE][64]   2 MB
    int* cnt      = (int*)(Ke + (size_t)EE * TK);      // [NN]       16 KB
    int2* elist2  = (int2*)(cnt + NN);                 // [NN][CAP]  1 MB

    hipLaunchKernelGGL(irf_zero_kernel, dim3(1040), dim3(256), 0, stream, params, hirf, cnt);
    hipLaunchKernelGGL(kedge_scatter_kernel, dim3(EE / 4), dim3(256), 0, stream,
                       hirf, esrc, etgt, Ke, cnt, elist2);
    hipLaunchKernelGGL(conv_mfma_kernel, dim3(NN * 2), dim3(128), 0, stream,
                       x, hirf, Ke, elist2, cnt, y);
}

// Round 8
// 52.523 us; speedup vs baseline: 2.4012x; 1.0253x over previous
//
#include <hip/hip_runtime.h>
#include <math.h>

// Problem constants (B=2, N=4096, T=2048, E=8192, MAX_DELAY=64)
static constexpr int NN = 4096;
static constexpr int TT = 2048;
static constexpr int EE = 8192;
static constexpr int TK = 64;
static constexpr int CAP = 32;                  // max in-degree (Poisson lam=2)

typedef __attribute__((ext_vector_type(8))) short        short8v;  // 8 bf16
typedef __attribute__((ext_vector_type(4))) float        float4v;  // MFMA acc
typedef __attribute__((ext_vector_type(2))) unsigned int uint2v;

__device__ __forceinline__ unsigned cvtpk_bf16(float lo, float hi) {
    unsigned r;                      // D[15:0]=bf16(lo), D[31:16]=bf16(hi), RNE
    asm("v_cvt_pk_bf16_f32 %0, %1, %2" : "=v"(r) : "v"(lo), "v"(hi));
    return r;
}

// ---------------------------------------------------------------------------
// K1: fused prep.
//   blocks [0,1024):    convert x fp32 -> xb bf16.  x = 4,194,304 float4;
//                       1024 blk x 256 thr x 16 f4 = 4,194,304 exactly.
//   blocks [1024,2048): per-node IRF -> hirf fp32 + hb bf16
//   blocks [2048,2064): zero cnt
// ---------------------------------------------------------------------------
__global__ void prep_kernel(const float* __restrict__ params,
                            const float* __restrict__ x,
                            float* __restrict__ hirf, unsigned short* __restrict__ hb,
                            unsigned short* __restrict__ xb, int* __restrict__ cnt,
                            int doX) {
    int blk = blockIdx.x;
    if (blk < 1024) {                           // x convert: 16 float4/thread
        if (!doX) return;
        const float4* src = reinterpret_cast<const float4*>(x) + (size_t)blk * 4096 + threadIdx.x;
        uint2v*       dst = reinterpret_cast<uint2v*>(xb) + (size_t)blk * 4096 + threadIdx.x;
        #pragma unroll
        for (int c = 0; c < 16; ++c) {
            float4 v = src[c * 256];
            uint2v o; o.x = cvtpk_bf16(v.x, v.y); o.y = cvtpk_bf16(v.z, v.w);
            dst[c * 256] = o;
        }
    } else if (blk < 2048) {                    // IRF
        int t = (blk - 1024) * 256 + threadIdx.x;
        int node = t >> 6, lane = t & 63;
        float p = params[node * 2];
        float sp = fmaxf(p, 0.f) + log1pf(expf(-fabsf(p)));   // stable softplus
        float kst = sp + 0.1f;
        float inv = 1.0f / kst;
        float hv = expf(-(float)lane * inv) * inv;
        float s = hv;
        #pragma unroll
        for (int d = 1; d < 64; d <<= 1) s += __shfl_xor(s, d, 64);
        float val = hv / s;
        hirf[node * TK + lane] = val;
        hb[node * TK + lane] = (unsigned short)(cvtpk_bf16(val, val) & 0xffffu);
    } else {                                    // zero cnt
        int i = (blk - 2048) * 256 + threadIdx.x;
        if (i < NN) cnt[i] = 0;
    }
}

// ---------------------------------------------------------------------------
// K2: per-edge composed kernel (4 edges / 256-thr block) -> Kb bf16
//     + capped-list scatter (e, src) by target
// ---------------------------------------------------------------------------
__global__ void kedge_kernel(const float* __restrict__ hirf,
                             const int* __restrict__ esrc, const int* __restrict__ etgt,
                             unsigned short* __restrict__ Kb, int* __restrict__ cnt,
                             int2* __restrict__ elist2) {
    __shared__ float s_src[4][TK];
    __shared__ float s_tgt[4][TK];
    int lane = threadIdx.x & 63;
    int grp  = threadIdx.x >> 6;
    int e = blockIdx.x * 4 + grp;
    int s = esrc[e], t = etgt[e];
    s_src[grp][lane] = hirf[s * TK + lane];
    s_tgt[grp][lane] = hirf[t * TK + lane];
    __syncthreads();
    float acc = 0.f;
    for (int tau = 0; tau <= lane; ++tau)
        acc += s_tgt[grp][tau] * s_src[grp][lane - tau];
    Kb[e * TK + lane] = (unsigned short)(cvtpk_bf16(acc, acc) & 0xffffu);
    if (lane == 0) {
        int pos = atomicAdd(&cnt[t], 1);
        if (pos < CAP) elist2[t * CAP + pos] = make_int2(e, s);
    }
}

// ---------------------------------------------------------------------------
// K3: polyphase MFMA conv (round-6 proven pipeline; load dtype templated).
// One block per (target, batch); 128 thr = 2 waves (wave = time-half).
// Double-buffered LDS {x bf16, K-Toeplitz tab}; 2-deep register prefetch.
// BF16X=1: x rows gathered from pre-converted xb (HALF the load-path bytes,
// pure ds_write_b128 staging).  BF16X=0: fp32 x + cvt_pk (fallback if ws
// is too small for xb).
//
//   y[16a+r] = sum_{delta,p} C[r][16*delta+p] * xrow[16*(a-delta)+p]
//   C[r][16*delta+p] = K_clip[r - p + 16*delta]     (zero outside [0,64))
// ---------------------------------------------------------------------------
static constexpr int HALO = 80;                 // covers delta<=5 lookback
static constexpr int XLEN = HALO + TT;          // 2128 bf16
static constexpr int TABS = 96;
static constexpr int TABE = TABS * 16;          // 1536

struct __align__(16) ConvBuf {
    unsigned short x[XLEN];                     // 4256 B
    unsigned short tab[TABE];                   // 3072 B
};                                              // 7328 B; x2 bufs = 14656 B

template <int BF16X>
__global__ __launch_bounds__(128)
void conv_mfma_kernel(const float* __restrict__ x32,
                      const unsigned short* __restrict__ xb,
                      const unsigned short* __restrict__ hb,
                      const unsigned short* __restrict__ Kb,
                      const int2* __restrict__ elist2,
                      const int* __restrict__ cnt,
                      float* __restrict__ y) {
    __shared__ ConvBuf sbuf[2];

    const int tid    = threadIdx.x;
    const int bid    = blockIdx.x;
    const int b      = bid & 1;                 // batch
    const int tgt    = bid >> 1;
    const int l      = tid & 63;
    const int lane16 = l & 15;
    const int h      = l >> 4;
    const int hlo    = h & 1, hhi = h >> 1;
    const int half   = tid >> 6;                // time half (wave id)

    // one-time init: x halos + static tab zero entries, both buffers
    for (int idx = tid; idx < 2 * HALO; idx += 128) {
        int nb = idx / HALO;
        sbuf[nb].x[idx % HALO] = 0;
    }
    {
        int z = tid & 15;
        #pragma unroll
        for (int rr = 0; rr < 2; ++rr) {
            int r2 = (tid >> 4) + 8 * rr;       // rows 0..15
            int c1 = z, c2 = (z <= r2) ? z + 16 : 80 + z;
            sbuf[0].tab[TABS * r2 + c1] = 0; sbuf[0].tab[TABS * r2 + c2] = 0;
            sbuf[1].tab[TABS * r2 + c1] = 0; sbuf[1].tab[TABS * r2 + c2] = 0;
        }
    }

    float4v acc[4];
    #pragma unroll
    for (int T = 0; T < 4; ++T) acc[T] = (float4v){0.f, 0.f, 0.f, 0.f};

    float4  pxA32[4], pxB32[4];
    short8v pxA16[2], pxB16[2];
    unsigned short pkA, pkB;

    auto LOAD_A = [&](int src, const unsigned short* Kp) {
        if constexpr (BF16X) {
            const short8v* r = reinterpret_cast<const short8v*>(xb + ((size_t)b * NN + src) * TT);
            pxA16[0] = r[tid]; pxA16[1] = r[tid + 128];
        } else {
            const float4* r = reinterpret_cast<const float4*>(x32 + ((size_t)b * NN + src) * TT);
            #pragma unroll
            for (int c = 0; c < 4; ++c) pxA32[c] = r[tid + 128 * c];
        }
        pkA = Kp[l];
    };
    auto LOAD_B = [&](int src, const unsigned short* Kp) {
        if constexpr (BF16X) {
            const short8v* r = reinterpret_cast<const short8v*>(xb + ((size_t)b * NN + src) * TT);
            pxB16[0] = r[tid]; pxB16[1] = r[tid + 128];
        } else {
            const float4* r = reinterpret_cast<const float4*>(x32 + ((size_t)b * NN + src) * TT);
            #pragma unroll
            for (int c = 0; c < 4; ++c) pxB32[c] = r[tid + 128 * c];
        }
        pkB = Kp[l];
    };
    auto WRITE_A = [&](int nb) {
        if constexpr (BF16X) {
            *reinterpret_cast<short8v*>(&sbuf[nb].x[HALO + 8 * tid])         = pxA16[0];
            *reinterpret_cast<short8v*>(&sbuf[nb].x[HALO + 8 * (tid + 128)]) = pxA16[1];
        } else {
            #pragma unroll
            for (int c = 0; c < 4; ++c) {
                int u = tid + 128 * c;
                unsigned lo = cvtpk_bf16(pxA32[c].x, pxA32[c].y);
                unsigned hi = cvtpk_bf16(pxA32[c].z, pxA32[c].w);
                *reinterpret_cast<uint2*>(&sbuf[nb].x[HALO + 4 * u]) = make_uint2(lo, hi);
            }
        }
        int rg = tid >> 6;
        #pragma unroll
        for (int rr = 0; rr < 8; ++rr) {
            int r = rg * 8 + rr;
            sbuf[nb].tab[TABS * r + 80 + r - l] = pkA;
        }
    };
    auto WRITE_B = [&](int nb) {
        if constexpr (BF16X) {
            *reinterpret_cast<short8v*>(&sbuf[nb].x[HALO + 8 * tid])         = pxB16[0];
            *reinterpret_cast<short8v*>(&sbuf[nb].x[HALO + 8 * (tid + 128)]) = pxB16[1];
        } else {
            #pragma unroll
            for (int c = 0; c < 4; ++c) {
                int u = tid + 128 * c;
                unsigned lo = cvtpk_bf16(pxB32[c].x, pxB32[c].y);
                unsigned hi = cvtpk_bf16(pxB32[c].z, pxB32[c].w);
                *reinterpret_cast<uint2*>(&sbuf[nb].x[HALO + 4 * u]) = make_uint2(lo, hi);
            }
        }
        int rg = tid >> 6;
        #pragma unroll
        for (int rr = 0; rr < 8; ++rr) {
            int r = rg * 8 + rr;
            sbuf[nb].tab[TABS * r + 80 + r - l] = pkB;
        }
    };
    auto COMPUTE = [&](int cb) {
        const unsigned short* tab = sbuf[cb].tab;
        const unsigned short* xv  = sbuf[cb].x;
        const int abase = TABS * lane16 + 80 + 8 * hlo;
        short8v A0 = *reinterpret_cast<const short8v*>(&tab[abase - 16 * (0 + hhi)]);
        short8v A1 = *reinterpret_cast<const short8v*>(&tab[abase - 16 * (2 + hhi)]);
        short8v A2 = *reinterpret_cast<const short8v*>(&tab[abase - 16 * (4 + hhi)]);
        #pragma unroll
        for (int T = 0; T < 4; ++T) {
            int bb = HALO + 16 * (64 * half + 16 * T + lane16) + 8 * hlo;
            short8v B0 = *reinterpret_cast<const short8v*>(&xv[bb - 16 * (0 + hhi)]);
            acc[T] = __builtin_amdgcn_mfma_f32_16x16x32_bf16(A0, B0, acc[T], 0, 0, 0);
            short8v B1 = *reinterpret_cast<const short8v*>(&xv[bb - 16 * (2 + hhi)]);
            acc[T] = __builtin_amdgcn_mfma_f32_16x16x32_bf16(A1, B1, acc[T], 0, 0, 0);
            short8v B2 = *reinterpret_cast<const short8v*>(&xv[bb - 16 * (4 + hhi)]);
            acc[T] = __builtin_amdgcn_mfma_f32_16x16x32_bf16(A2, B2, acc[T], 0, 0, 0);
        }
    };

    // ---- metadata + prologue ----
    int deg = __builtin_amdgcn_readfirstlane(cnt[tgt]);
    if (deg > CAP) deg = CAP;
    const int nr = deg + 1;                     // routes: self + edges
    int mdE = 0, mdS = 0;                       // metadata for next route to stage

    LOAD_A(tgt, hb + (size_t)tgt * TK);         // route 0 = self -> set A
    if (nr > 1) {
        int2 m = elist2[tgt * CAP];
        mdE = __builtin_amdgcn_readfirstlane(m.x);
        mdS = __builtin_amdgcn_readfirstlane(m.y);
        LOAD_B(mdS, Kb + (size_t)mdE * TK);     // route 1 -> set B
        if (nr > 2) {
            int2 m2 = elist2[tgt * CAP + 1];
            mdE = __builtin_amdgcn_readfirstlane(m2.x);
            mdS = __builtin_amdgcn_readfirstlane(m2.y);
        }
    }
    WRITE_A(0);                                 // pxA issued well before this wait
    __syncthreads();

    // ---- main loop: route r lives in buf[r&1], px set[r&1]; unroll 2 ----
    int i = 0;
    while (true) {
        // even i: compute route i (buf0); stage route i+2 into set A
        if (i + 2 < nr) {
            LOAD_A(mdS, Kb + (size_t)mdE * TK);
            if (i + 3 < nr) {
                int2 m = elist2[tgt * CAP + i + 2];
                mdE = __builtin_amdgcn_readfirstlane(m.x);
                mdS = __builtin_amdgcn_readfirstlane(m.y);
            }
        }
        COMPUTE(0);
        if (i + 1 >= nr) break;
        WRITE_B(1);                             // route i+1 (loads issued at i-1)
        __syncthreads();
        ++i;
        // odd i: compute route i (buf1); stage route i+2 into set B
        if (i + 2 < nr) {
            LOAD_B(mdS, Kb + (size_t)mdE * TK);
            if (i + 3 < nr) {
                int2 m = elist2[tgt * CAP + i + 2];
                mdE = __builtin_amdgcn_readfirstlane(m.x);
                mdS = __builtin_amdgcn_readfirstlane(m.y);
            }
        }
        COMPUTE(1);
        if (i + 1 >= nr) break;
        WRITE_A(0);
        __syncthreads();
        ++i;
    }

    float* yrow = y + ((size_t)b * NN + tgt) * TT;
    #pragma unroll
    for (int T = 0; T < 4; ++T) {
        int tb = 16 * (64 * half + 16 * T + lane16) + 4 * h;
        float4v v = acc[T];
        __builtin_nontemporal_store(v, reinterpret_cast<float4v*>(yrow + tb));
    }
}

// ---------------------------------------------------------------------------
extern "C" void kernel_launch(void* const* d_in, const int* in_sizes, int n_in,
                              void* d_out, int out_size, void* d_ws, size_t ws_size,
                              hipStream_t stream) {
    const float* x      = (const float*)d_in[0];
    const float* params = (const float*)d_in[1];
    const int*   esrc   = (const int*)d_in[2];
    const int*   etgt   = (const int*)d_in[3];
    float* y = (float*)d_out;

    char* w = (char*)d_ws;
    float*          hirf   = (float*)w;          w += (size_t)NN * TK * 4;   // 1 MB
    unsigned short* hb     = (unsigned short*)w; w += (size_t)NN * TK * 2;   // 0.5 MB
    unsigned short* Kb     = (unsigned short*)w; w += (size_t)EE * TK * 2;   // 1 MB
    int*            cnt    = (int*)w;            w += (size_t)NN * 4;        // 16 KB
    int2*           elist2 = (int2*)w;           w += (size_t)NN * CAP * 8;  // 1 MB
    unsigned short* xb     = (unsigned short*)w; w += (size_t)2 * NN * TT * 2; // 32 MB

    size_t need = (size_t)(w - (char*)d_ws);
    int doX = (ws_size >= need) ? 1 : 0;        // fall back to fp32 x if ws too small

    hipLaunchKernelGGL(prep_kernel, dim3(2064), dim3(256), 0, stream,
                       params, x, hirf, hb, xb, cnt, doX);
    hipLaunchKernelGGL(kedge_kernel, dim3(EE / 4), dim3(256), 0, stream,
                       hirf, esrc, etgt, Kb, cnt, elist2);
    if (doX) {
        hipLaunchKernelGGL((conv_mfma_kernel<1>), dim3(NN * 2), dim3(128), 0, stream,
                           x, xb, hb, Kb, elist2, cnt, y);
    } else {
        hipLaunchKernelGGL((conv_mfma_kernel<0>), dim3(NN * 2), dim3(128), 0, stream,
                           x, xb, hb, Kb, elist2, cnt, y);
    }
}